// Round 13
// baseline (909.792 us; speedup 1.0000x reference)
//
#include <hip/hip_runtime.h>

#define N_NODES 50000
#define N_EDGES 1600000
#define NREL 32
#define NBASES 8
#define DIN 128
#define DOUT 128
#define KTOT (NBASES * DIN)       // 1024
#define KSL  (KTOT + DIN)         // 1152 (self-loop folded in)
#define KPAD 1160                 // +8 bf16 (16B) row pad
#define NPB  16                   // nodes per block

typedef __attribute__((ext_vector_type(8))) short short8;
typedef __attribute__((ext_vector_type(4))) float f32x4;

static __device__ __forceinline__ ushort f2bf(float f) {   // RNE f32->bf16
    uint u = __float_as_uint(f);
    u += 0x7FFF + ((u >> 16) & 1);
    return (ushort)(u >> 16);
}

// ---------------- CSR build ----------------

__global__ void k_hist(const int* __restrict__ dst, int* __restrict__ deg) {
    int e = blockIdx.x * blockDim.x + threadIdx.x;
    if (e < N_EDGES) atomicAdd(&deg[dst[e]], 1);
}

__global__ void k_scan(const int* __restrict__ deg, int* __restrict__ indptr) {
    __shared__ int sdata[1024];
    const int T = 1024;
    int t = threadIdx.x;
    const int chunk = (N_NODES + T - 1) / T;
    int lo = t * chunk;
    int hi = lo + chunk; if (hi > N_NODES) hi = N_NODES;
    if (lo > N_NODES) lo = N_NODES;
    int s = 0;
    for (int i = lo; i < hi; ++i) s += deg[i];
    sdata[t] = s;
    __syncthreads();
    for (int off = 1; off < T; off <<= 1) {
        int v = (t >= off) ? sdata[t - off] : 0;
        __syncthreads();
        sdata[t] += v;
        __syncthreads();
    }
    int base = (t == 0) ? 0 : sdata[t - 1];
    for (int i = lo; i < hi; ++i) { indptr[i] = base; base += deg[i]; }
    if (t == T - 1) indptr[N_NODES] = sdata[T - 1];
}

__global__ void k_scatter(const int* __restrict__ dst,
                          const int* __restrict__ src,
                          const int* __restrict__ ety,
                          const int* __restrict__ indptr,
                          int* __restrict__ cursor,
                          int* __restrict__ packed) {
    int e = blockIdx.x * blockDim.x + threadIdx.x;
    if (e < N_EDGES) {
        int d = dst[e];
        int pos = atomicAdd(&cursor[d], 1);
        packed[indptr[d] + pos] = src[e] | (ety[e] << 16);
    }
}

// ---------------- weight pre-convert: wbT[n][k] bf16, [weight;loop_w]^T ----
__global__ void k_wconv(const float* __restrict__ weight,    // [1024][128]
                        const float* __restrict__ loop_w,    // [128][128]
                        ushort* __restrict__ wbT) {          // [128][1152]
    const int e = blockIdx.x * blockDim.x + threadIdx.x;     // 147456 exact
    const int k = e >> 7;
    const int n = e & 127;
    const float v = (k < KTOT) ? weight[e] : loop_w[e - KTOT * DIN];
    wbT[n * KSL + k] = f2bf(v);
}

// ---------------- fused aggregate + project (DIAGNOSTIC VALU phase 2) ----
// Identical phase 1 + wbT to round 10 (the failing MFMA kernel); phase 2
// replaced by a VALU fp32 sum consuming THE SAME bf16 tmp16 + bf16 wbT.
// This is mathematically what the MFMA should compute:
//   PASS  -> data path good; bug is in MFMA fragment consumption.
//   FAIL  -> data path (f2bf / wbT / ws-placement / NPB=16 phase 1) broken.

#define EDGE_FMA(P, XV)                                                      \
    do {                                                                     \
        const float4 wA_ = *(const float4*)&wc[((P) >> 16) * NBASES];        \
        const float4 wB_ = *(const float4*)&wc[((P) >> 16) * NBASES + 4];    \
        a0x += wA_.x * (XV).x; a0y += wA_.x * (XV).y;                        \
        a1x += wA_.y * (XV).x; a1y += wA_.y * (XV).y;                        \
        a2x += wA_.z * (XV).x; a2y += wA_.z * (XV).y;                        \
        a3x += wA_.w * (XV).x; a3y += wA_.w * (XV).y;                        \
        a4x += wB_.x * (XV).x; a4y += wB_.x * (XV).y;                        \
        a5x += wB_.y * (XV).x; a5y += wB_.y * (XV).y;                        \
        a6x += wB_.z * (XV).x; a6y += wB_.z * (XV).y;                        \
        a7x += wB_.w * (XV).x; a7y += wB_.w * (XV).y;                        \
    } while (0)

// bf16 pair (in a uint2) dotted against 4 fp32 weights, accumulated into OJ
#define ROWACC(J, OJ)                                                        \
    {                                                                        \
        const uint2 tp = *(const uint2*)&tmp16[half + 2 * (J)][k];           \
        OJ += __uint_as_float(tp.x << 16) * w0                               \
            + __uint_as_float(tp.x & 0xFFFF0000u) * w1                       \
            + __uint_as_float(tp.y << 16) * w2                               \
            + __uint_as_float(tp.y & 0xFFFF0000u) * w3;                      \
    }

__launch_bounds__(256, 2)
__global__ void k_fused(const float* __restrict__ x,
                        const float* __restrict__ w_comp,    // [32][8]
                        const float* __restrict__ h_bias,    // [128]
                        const int* __restrict__ indptr,
                        const int* __restrict__ packed,
                        const ushort* __restrict__ wbT,      // [128][1152] bf16
                        float* __restrict__ out) {
    __shared__ float wc[NREL * NBASES];                      // 1 KB
    __shared__ __align__(16) ushort tmp16[NPB][KPAD];        // 36.25 KB

    const int tid  = threadIdx.x;
    const int lane = tid & 63;
    const int wid  = tid >> 6;                 // 0..3
    const int nbase = blockIdx.x * NPB;

    wc[tid] = w_comp[tid];                     // 256 == blockDim
    __syncthreads();

    // ---- Phase 1: aggregation (fp32 regs -> bf16 LDS), round-9 structure ----
    for (int rep = 0; rep < 4; ++rep) {
        const int nl = rep * 4 + wid;
        const int node = nbase + nl;
        float a0x = 0.f, a0y = 0.f, a1x = 0.f, a1y = 0.f;
        float a2x = 0.f, a2y = 0.f, a3x = 0.f, a3y = 0.f;
        float a4x = 0.f, a4y = 0.f, a5x = 0.f, a5y = 0.f;
        float a6x = 0.f, a6y = 0.f, a7x = 0.f, a7y = 0.f;

        {
            const float2 xs = *(const float2*)&x[(size_t)node * DIN + 2 * lane];
            *(uint*)&tmp16[nl][KTOT + 2 * lane] =
                (uint)f2bf(xs.x) | ((uint)f2bf(xs.y) << 16);
        }

        const int beg = indptr[node], end = indptr[node + 1];
        for (int base = beg; base < end; base += 64) {
            const int cnt = min(64, end - base);
            int pk = 0;
            if (base + lane < end) pk = packed[base + lane];
            int j = 0;
            for (; j + 4 <= cnt; j += 4) {
                const int p0 = __shfl(pk, j + 0);
                const int p1 = __shfl(pk, j + 1);
                const int p2 = __shfl(pk, j + 2);
                const int p3 = __shfl(pk, j + 3);
                const float2 x0 = *(const float2*)&x[(size_t)(p0 & 0xFFFF) * DIN + 2 * lane];
                const float2 x1 = *(const float2*)&x[(size_t)(p1 & 0xFFFF) * DIN + 2 * lane];
                const float2 x2 = *(const float2*)&x[(size_t)(p2 & 0xFFFF) * DIN + 2 * lane];
                const float2 x3 = *(const float2*)&x[(size_t)(p3 & 0xFFFF) * DIN + 2 * lane];
                EDGE_FMA(p0, x0);
                EDGE_FMA(p1, x1);
                EDGE_FMA(p2, x2);
                EDGE_FMA(p3, x3);
            }
            for (; j < cnt; ++j) {
                const int p0 = __shfl(pk, j);
                const float2 x0 = *(const float2*)&x[(size_t)(p0 & 0xFFFF) * DIN + 2 * lane];
                EDGE_FMA(p0, x0);
            }
        }
        *(uint*)&tmp16[nl][0 * DIN + 2 * lane] = (uint)f2bf(a0x) | ((uint)f2bf(a0y) << 16);
        *(uint*)&tmp16[nl][1 * DIN + 2 * lane] = (uint)f2bf(a1x) | ((uint)f2bf(a1y) << 16);
        *(uint*)&tmp16[nl][2 * DIN + 2 * lane] = (uint)f2bf(a2x) | ((uint)f2bf(a2y) << 16);
        *(uint*)&tmp16[nl][3 * DIN + 2 * lane] = (uint)f2bf(a3x) | ((uint)f2bf(a3y) << 16);
        *(uint*)&tmp16[nl][4 * DIN + 2 * lane] = (uint)f2bf(a4x) | ((uint)f2bf(a4y) << 16);
        *(uint*)&tmp16[nl][5 * DIN + 2 * lane] = (uint)f2bf(a5x) | ((uint)f2bf(a5y) << 16);
        *(uint*)&tmp16[nl][6 * DIN + 2 * lane] = (uint)f2bf(a6x) | ((uint)f2bf(a6y) << 16);
        *(uint*)&tmp16[nl][7 * DIN + 2 * lane] = (uint)f2bf(a7x) | ((uint)f2bf(a7y) << 16);
    }
    __syncthreads();

    // ---- Phase 2 (VALU diagnostic): [16 x 1152] @ wbT^T in fp32 ----
    const int d = tid & 127;
    const int half = tid >> 7;               // rows half+2j, j=0..7
    float o0 = 0.f, o1 = 0.f, o2 = 0.f, o3 = 0.f;
    float o4 = 0.f, o5 = 0.f, o6 = 0.f, o7 = 0.f;

    const ushort* wrow = &wbT[(size_t)d * KSL];
    for (int k = 0; k < KSL; k += 4) {
        const uint2 wp = *(const uint2*)(wrow + k);
        const float w0 = __uint_as_float(wp.x << 16);
        const float w1 = __uint_as_float(wp.x & 0xFFFF0000u);
        const float w2 = __uint_as_float(wp.y << 16);
        const float w3 = __uint_as_float(wp.y & 0xFFFF0000u);
        ROWACC(0, o0); ROWACC(1, o1); ROWACC(2, o2); ROWACC(3, o3);
        ROWACC(4, o4); ROWACC(5, o5); ROWACC(6, o6); ROWACC(7, o7);
    }

    const float bias = h_bias[d];
    out[(size_t)(nbase + half +  0) * DOUT + d] = fmaxf(o0 + bias, 0.f);
    out[(size_t)(nbase + half +  2) * DOUT + d] = fmaxf(o1 + bias, 0.f);
    out[(size_t)(nbase + half +  4) * DOUT + d] = fmaxf(o2 + bias, 0.f);
    out[(size_t)(nbase + half +  6) * DOUT + d] = fmaxf(o3 + bias, 0.f);
    out[(size_t)(nbase + half +  8) * DOUT + d] = fmaxf(o4 + bias, 0.f);
    out[(size_t)(nbase + half + 10) * DOUT + d] = fmaxf(o5 + bias, 0.f);
    out[(size_t)(nbase + half + 12) * DOUT + d] = fmaxf(o6 + bias, 0.f);
    out[(size_t)(nbase + half + 14) * DOUT + d] = fmaxf(o7 + bias, 0.f);
}

// ---------------- launch ----------------

extern "C" void kernel_launch(void* const* d_in, const int* in_sizes, int n_in,
                              void* d_out, int out_size, void* d_ws, size_t ws_size,
                              hipStream_t stream) {
    const float* x      = (const float*)d_in[0];
    const int*   src    = (const int*)  d_in[1];
    const int*   dst    = (const int*)  d_in[2];
    const int*   ety    = (const int*)  d_in[3];
    const float* weight = (const float*)d_in[4];
    const float* w_comp = (const float*)d_in[5];
    const float* h_bias = (const float*)d_in[6];
    const float* loop_w = (const float*)d_in[7];
    float* out = (float*)d_out;

    int* deg    = (int*)d_ws;                 // N
    int* indptr = deg + N_NODES;              // N+1
    int* cursor = indptr + N_NODES + 1;       // N
    int* packed = cursor + N_NODES;           // E
    const size_t woff = ((size_t)(3 * N_NODES + 1 + N_EDGES) + 15) & ~(size_t)15;
    ushort* wbT = (ushort*)((int*)d_ws + woff);   // 128*1152 bf16 (295 KB)

    hipMemsetAsync(d_ws, 0, (size_t)(3 * N_NODES + 1) * sizeof(int), stream);

    k_wconv<<<(DOUT * KSL) / 256, 256, 0, stream>>>(weight, loop_w, wbT);
    k_hist<<<(N_EDGES + 255) / 256, 256, 0, stream>>>(dst, deg);
    k_scan<<<1, 1024, 0, stream>>>(deg, indptr);
    k_scatter<<<(N_EDGES + 255) / 256, 256, 0, stream>>>(dst, src, ety, indptr, cursor, packed);
    k_fused<<<N_NODES / NPB, 256, 0, stream>>>(
        x, w_comp, h_bias, indptr, packed, wbT, out);
}